// Round 5
// baseline (14240.028 us; speedup 1.0000x reference)
//
#include <hip/hip_runtime.h>
#include <hip/hip_cooperative_groups.h>

namespace cg = cooperative_groups;

// GRU (reverse scan), B=128 T=1024 H=256. Inputs fp32, OUTPUT fp32 (reference
// output dtype is float32 -- rounds 2-4 failed only because we wrote bf16).
// Cooperative persistent kernel: 32 WGs = batch-split 2 x hidden-split 16.
// Compensated bf16 MFMA: operands split hi/lo, GEMM = hi*hi + lo*hi + hi*lo.
// Weight hi/lo slices in dynamic LDS (101 KB, 1 WG/CU). h kept fp32 in ws,
// double-buffered; grid-wide sync via cooperative groups grid.sync().

#define TT 1024
#define BB 128
#define HH 256

typedef unsigned short u16;
typedef __attribute__((ext_vector_type(8))) short  bf16x8;
typedef __attribute__((ext_vector_type(4))) float  f32x4;

static constexpr int NWG_B  = 2;
static constexpr int NWG_H  = 16;
static constexpr int NWG    = NWG_B * NWG_H;   // 32 workgroups
static constexpr int BS     = BB / NWG_B;      // 64 batch rows per WG
static constexpr int HS     = HH / NWG_H;      // 16 hidden cols per WG
static constexpr int WPITCH = HH + 8;          // LDS row pitch 264 (16B-aligned, conflict pad)
static constexpr int LO_OFF = 96 * WPITCH;     // lo-plane offset in LDS elements
static constexpr int LDS_BYTES = 192 * WPITCH * 2;  // 101376 B

__device__ __forceinline__ float b2f(u16 u) {
  union { unsigned i; float f; } v; v.i = ((unsigned)u) << 16; return v.f;
}
__device__ __forceinline__ u16 f2b(float f) {   // RNE fp32 -> bf16
  union { float f; unsigned i; } v; v.f = f;
  return (u16)((v.i + 0x7fffu + ((v.i >> 16) & 1u)) >> 16);
}
__device__ __forceinline__ float sigm(float x) { return 1.0f / (1.0f + __expf(-x)); }
__device__ __forceinline__ float tanh_fast(float x) {
  float a = fabsf(x);
  float e = __expf(-2.0f * a);          // in (0,1], no overflow
  float t = (1.0f - e) / (1.0f + e);
  return copysignf(t, x);
}
__device__ __forceinline__ void split8(const float* p, bf16x8& hi, bf16x8& lo) {
  f32x4 a = *(const f32x4*)p;
  f32x4 b = *(const f32x4*)(p + 4);
  union { bf16x8 v; u16 e[8]; } uh, ul;
#pragma unroll
  for (int j = 0; j < 4; ++j) {
    const u16 h0 = f2b(a[j]); uh.e[j]     = h0; ul.e[j]     = f2b(a[j] - b2f(h0));
    const u16 h1 = f2b(b[j]); uh.e[4 + j] = h1; ul.e[4 + j] = f2b(b[j] - b2f(h1));
  }
  hi = uh.v; lo = ul.v;
}

__global__ void __launch_bounds__(256, 1)
gru_persist(const float* __restrict__ m_enc,
            const float* __restrict__ w_ih,
            const float* __restrict__ w_hh,
            const float* __restrict__ b_ih,
            const float* __restrict__ b_hh,
            float* __restrict__ out,
            float* __restrict__ hbuf)   // [2][BB][HH] fp32
{
  extern __shared__ u16 lds_w[];      // [192][WPITCH]; rows 0..95 hi, 96..191 lo
                                      // row = m*48 + g*16 + rr (m: 0=w_ih 1=w_hh, g: r/z/n)
  cg::grid_group grid = cg::this_grid();

  const int tid  = threadIdx.x;
  const int wave = tid >> 6;
  const int lane = tid & 63;
  const int wg   = blockIdx.x;
  const int bi   = wg & 1;            // batch half
  const int hj   = wg >> 1;           // hidden slice 0..15
  const int col0 = hj * HS;

  // ---- stage weight slices into LDS as hi/lo bf16 (one-time) ----
  for (int r = wave; r < 96; r += 4) {
    const int m  = r / 48;            // 0 = w_ih, 1 = w_hh
    const int g  = (r % 48) / 16;     // gate 0=r,1=z,2=n
    const int rr = r % 16;
    const float* src = (m ? w_hh : w_ih) + (size_t)(g * HH + col0 + rr) * HH;
    u16* dhi = &lds_w[r * WPITCH];
    u16* dlo = &lds_w[LO_OFF + r * WPITCH];
    for (int c = lane; c < HH; c += 64) {
      const float f  = src[c];
      const u16 hi   = f2b(f);
      dhi[c] = hi;
      dlo[c] = f2b(f - b2f(hi));
    }
  }
  __syncthreads();

  // ---- per-lane constants ----
  const int arow = lane & 15;         // A-frag row / D-col index
  const int quad = lane >> 4;         // 0..3
  const int row0 = bi * BS + wave * 16;     // wave's 16-row batch tile
  const int cd   = col0 + arow;             // hidden column (D layout: col = lane&15)

  const float bsum_r = b_ih[cd]          + b_hh[cd];
  const float bsum_z = b_ih[HH + cd]     + b_hh[HH + cd];
  const float bi_n   = b_ih[2 * HH + cd];
  const float bh_n   = b_hh[2 * HH + cd];

  const int abrow = row0 + arow;                       // this lane's A row (batch)
  const float* xrowbase = m_enc + (size_t)abrow * TT * HH + quad * 8;

  // B-frag LDS element offsets (hi plane) for (matrix m, gate g)
  int woff[2][3];
#pragma unroll
  for (int m = 0; m < 2; ++m)
#pragma unroll
    for (int g = 0; g < 3; ++g)
      woff[m][g] = (m * 48 + g * 16 + arow) * WPITCH + quad * 8;

  for (int s = 0; s < TT; ++s) {
    const int ts   = TT - 1 - s;
    const int rbuf = s & 1;
    const int wbuf = rbuf ^ 1;

    // ---- A fragments: x and h (fp32 -> bf16 hi/lo) ----
    bf16x8 xhi[8], xlo[8], hhi[8], hlo[8];
    const float* xp = xrowbase + (size_t)ts * HH;
    const float* hp = hbuf + (size_t)rbuf * BB * HH + (size_t)abrow * HH + quad * 8;
#pragma unroll
    for (int kf = 0; kf < 8; ++kf) {
      split8(xp + kf * 32, xhi[kf], xlo[kf]);
      split8(hp + kf * 32, hhi[kf], hlo[kf]);
    }

    f32x4 air = {0.f,0.f,0.f,0.f}, aiz = {0.f,0.f,0.f,0.f}, ain = {0.f,0.f,0.f,0.f};
    f32x4 ahr = {0.f,0.f,0.f,0.f}, ahz = {0.f,0.f,0.f,0.f}, ahn = {0.f,0.f,0.f,0.f};
#pragma unroll
    for (int kf = 0; kf < 8; ++kf) {
      const int ko = kf * 32;
      // gi: x @ W_ih^T  (hi*hi + lo*hi + hi*lo)
      bf16x8 wr = *(const bf16x8*)&lds_w[woff[0][0] + ko];
      bf16x8 wz = *(const bf16x8*)&lds_w[woff[0][1] + ko];
      bf16x8 wn = *(const bf16x8*)&lds_w[woff[0][2] + ko];
      air = __builtin_amdgcn_mfma_f32_16x16x32_bf16(xhi[kf], wr, air, 0, 0, 0);
      aiz = __builtin_amdgcn_mfma_f32_16x16x32_bf16(xhi[kf], wz, aiz, 0, 0, 0);
      ain = __builtin_amdgcn_mfma_f32_16x16x32_bf16(xhi[kf], wn, ain, 0, 0, 0);
      air = __builtin_amdgcn_mfma_f32_16x16x32_bf16(xlo[kf], wr, air, 0, 0, 0);
      aiz = __builtin_amdgcn_mfma_f32_16x16x32_bf16(xlo[kf], wz, aiz, 0, 0, 0);
      ain = __builtin_amdgcn_mfma_f32_16x16x32_bf16(xlo[kf], wn, ain, 0, 0, 0);
      bf16x8 wrl = *(const bf16x8*)&lds_w[LO_OFF + woff[0][0] + ko];
      bf16x8 wzl = *(const bf16x8*)&lds_w[LO_OFF + woff[0][1] + ko];
      bf16x8 wnl = *(const bf16x8*)&lds_w[LO_OFF + woff[0][2] + ko];
      air = __builtin_amdgcn_mfma_f32_16x16x32_bf16(xhi[kf], wrl, air, 0, 0, 0);
      aiz = __builtin_amdgcn_mfma_f32_16x16x32_bf16(xhi[kf], wzl, aiz, 0, 0, 0);
      ain = __builtin_amdgcn_mfma_f32_16x16x32_bf16(xhi[kf], wnl, ain, 0, 0, 0);
      // gh: h @ W_hh^T  (hi*hi + lo*hi + hi*lo)
      bf16x8 vr = *(const bf16x8*)&lds_w[woff[1][0] + ko];
      bf16x8 vz = *(const bf16x8*)&lds_w[woff[1][1] + ko];
      bf16x8 vn = *(const bf16x8*)&lds_w[woff[1][2] + ko];
      ahr = __builtin_amdgcn_mfma_f32_16x16x32_bf16(hhi[kf], vr, ahr, 0, 0, 0);
      ahz = __builtin_amdgcn_mfma_f32_16x16x32_bf16(hhi[kf], vz, ahz, 0, 0, 0);
      ahn = __builtin_amdgcn_mfma_f32_16x16x32_bf16(hhi[kf], vn, ahn, 0, 0, 0);
      ahr = __builtin_amdgcn_mfma_f32_16x16x32_bf16(hlo[kf], vr, ahr, 0, 0, 0);
      ahz = __builtin_amdgcn_mfma_f32_16x16x32_bf16(hlo[kf], vz, ahz, 0, 0, 0);
      ahn = __builtin_amdgcn_mfma_f32_16x16x32_bf16(hlo[kf], vn, ahn, 0, 0, 0);
      bf16x8 vrl = *(const bf16x8*)&lds_w[LO_OFF + woff[1][0] + ko];
      bf16x8 vzl = *(const bf16x8*)&lds_w[LO_OFF + woff[1][1] + ko];
      bf16x8 vnl = *(const bf16x8*)&lds_w[LO_OFF + woff[1][2] + ko];
      ahr = __builtin_amdgcn_mfma_f32_16x16x32_bf16(hhi[kf], vrl, ahr, 0, 0, 0);
      ahz = __builtin_amdgcn_mfma_f32_16x16x32_bf16(hhi[kf], vzl, ahz, 0, 0, 0);
      ahn = __builtin_amdgcn_mfma_f32_16x16x32_bf16(hhi[kf], vnl, ahn, 0, 0, 0);
    }

    // ---- gates + state update (D layout: row = quad*4 + i, col = lane&15) ----
    float*       hw = hbuf + (size_t)wbuf * BB * HH;
    const float* hr = hbuf + (size_t)rbuf * BB * HH;
#pragma unroll
    for (int i = 0; i < 4; ++i) {
      const int rb = row0 + quad * 4 + i;
      const float hold = hr[(size_t)rb * HH + cd];
      const float rg = sigm(air[i] + ahr[i] + bsum_r);
      const float zg = sigm(aiz[i] + ahz[i] + bsum_z);
      const float ng = tanh_fast(ain[i] + bi_n + rg * (ahn[i] + bh_n));
      const float hnew = (1.0f - zg) * ng + zg * hold;
      out[((size_t)rb * TT + ts) * HH + cd] = hnew;   // fp32 output
      hw[(size_t)rb * HH + cd] = hnew;
    }

    // ---- grid-wide barrier (cooperative groups; handles all fencing) ----
    grid.sync();
  }
}

extern "C" void kernel_launch(void* const* d_in, const int* in_sizes, int n_in,
                              void* d_out, int out_size, void* d_ws, size_t ws_size,
                              hipStream_t stream) {
  const float* m_enc = (const float*)d_in[0];
  const float* w_ih  = (const float*)d_in[1];
  const float* w_hh  = (const float*)d_in[2];
  const float* b_ih  = (const float*)d_in[3];
  const float* b_hh  = (const float*)d_in[4];
  float* out = (float*)d_out;                      // reference output dtype: float32
  float* hbuf = (float*)d_ws;                      // [2][128][256] fp32 = 256 KiB

  hipFuncSetAttribute((const void*)gru_persist,
                      hipFuncAttributeMaxDynamicSharedMemorySize, LDS_BYTES);

  // h0 = 0 in both buffers; ws is re-poisoned before every call
  hipMemsetAsync(d_ws, 0, 2 * (size_t)BB * HH * sizeof(float), stream);

  void* args[] = { (void*)&m_enc, (void*)&w_ih, (void*)&w_hh,
                   (void*)&b_ih, (void*)&b_hh, (void*)&out, (void*)&hbuf };
  hipLaunchCooperativeKernel((const void*)gru_persist, dim3(NWG), dim3(256),
                             args, LDS_BYTES, stream);
}